// Round 8
// baseline (106957.373 us; speedup 1.0000x reference)
//
#include <hip/hip_runtime.h>
#include <hip/hip_bf16.h>

// MemoryLSTM: B=32, S=128, I=512, H=512, M=256, V=100000
// cvt_f16:   Xh,Wh = f16(X), f16(W_ih)
// gemm_mfma: Gb[4096][2048](f16) = Xh @ Wh^T + b_ih + b_hh   (MFMA 16x16x32 f16)
// prep_prev: prev[t] = latest t'<t with tok[t']==tok[t] (else -1)
// lstm_pipe: 32 sentences x 8 WGs x 512 thr, all concurrent.
//            GEMV via f16 MFMA, single pass (f16 quant err ~8x below bf16 ->
//            no residual MFMA; 64 -> 32 MFMAs/wave/step).
//            h publish: ALWAYS device-scope (proven R5/R6 path).
//            h poll: L2-scope (sc0) when the sentence's 8 WGs share an XCD
//            (runtime-verified via XCC_ID table) with a spin-count fallback
//            to device-scope -> deadlock-proof regardless of cache semantics.

#define T_TOTAL 4096
#define Ssz 128
#define HID 512
#define RDIM 2048
#define KDIM 512
#define MSZ 256
#define NX (1 << 21)   // X elements (32*128*512)

typedef unsigned long long u64;
typedef unsigned int u32;
typedef unsigned short u16;
typedef _Float16 f16;
typedef __attribute__((ext_vector_type(8))) _Float16 f16x8;
typedef __attribute__((ext_vector_type(4))) float f32x4;

__device__ __forceinline__ u16 f2h(float x) {
  union { f16 h; u16 u; } c; c.h = (f16)x; return c.u;
}
__device__ __forceinline__ float h2f(u16 b) {
  union { f16 h; u16 u; } c; c.u = b; return (float)c.h;
}
__device__ __forceinline__ float sigm_f(float x) {
  return __builtin_amdgcn_rcpf(1.f + __expf(-x));
}
__device__ __forceinline__ float tanh_f(float x) {
  return 1.f - 2.f * __builtin_amdgcn_rcpf(1.f + __expf(2.f * x));
}

// Device-scope (die-level coherent) ops: sc0 sc1. Stamped words self-validate.
__device__ __forceinline__ u32 ld32_dev(const u32* p) {
  u32 v;
  asm volatile("global_load_dword %0, %1, off sc0 sc1\n\ts_waitcnt vmcnt(0)"
               : "=v"(v) : "v"(p) : "memory");
  return v;
}
__device__ __forceinline__ void st32_dev(u32* p, u32 v) {
  asm volatile("global_store_dword %0, %1, off sc0 sc1" :: "v"(p), "v"(v) : "memory");
}
__device__ __forceinline__ u64 ld64_dev(const u64* p) {
  u64 v;
  asm volatile("global_load_dwordx2 %0, %1, off sc0 sc1\n\ts_waitcnt vmcnt(0)"
               : "=v"(v) : "v"(p) : "memory");
  return v;
}
__device__ __forceinline__ void st64_dev(u64* p, u64 v) {
  asm volatile("global_store_dwordx2 %0, %1, off sc0 sc1" :: "v"(p), "v"(v) : "memory");
}
// L2-scope load (sc0 only: L1 bypass, served by the XCD's L2). Poll fast path.
__device__ __forceinline__ u32 ld32_l2(const u32* p) {
  u32 v;
  asm volatile("global_load_dword %0, %1, off sc0\n\ts_waitcnt vmcnt(0)"
               : "=v"(v) : "v"(p) : "memory");
  return v;
}

// ---------------- fp32 -> f16 convert (X ++ W_ih) ----------------
__global__ __launch_bounds__(256) void cvt_f16(
    const float* __restrict__ X, const float* __restrict__ W,
    u16* __restrict__ dst)
{
  const int i = (blockIdx.x * 256 + threadIdx.x) * 4;
  const float* s = (i < NX) ? &X[i] : &W[i - NX];
  const float4 v = *(const float4*)s;
  ushort4 o;
  o.x = f2h(v.x); o.y = f2h(v.y); o.z = f2h(v.z); o.w = f2h(v.w);
  *(ushort4*)&dst[i] = o;
}

// ---------------- Gb = f16(Xh @ Wh^T + b_ih + b_hh), MFMA ----------------
__global__ __launch_bounds__(256) void gemm_mfma(
    const u16* __restrict__ Xh, const u16* __restrict__ Wh,
    const float* __restrict__ b_ih, const float* __restrict__ b_hh,
    u16* __restrict__ Gb)
{
  const int tid = threadIdx.x;
  const int wave = tid >> 6;
  const int lane = tid & 63;
  const int wm = wave >> 1, wn = wave & 1;
  const int m0 = blockIdx.x * 64 + wm * 32;
  const int n0 = blockIdx.y * 64 + wn * 32;
  const int fr = lane & 15;
  const int kc = lane >> 4;

  f32x4 acc[2][2] = {};
  const u16* ax0 = &Xh[(size_t)(m0 + fr) * KDIM + kc * 8];
  const u16* ax1 = ax0 + 16 * KDIM;
  const u16* bx0 = &Wh[(size_t)(n0 + fr) * KDIM + kc * 8];
  const u16* bx1 = bx0 + 16 * KDIM;
#pragma unroll
  for (int k0 = 0; k0 < KDIM; k0 += 32) {
    const f16x8 a0 = *(const f16x8*)(ax0 + k0);
    const f16x8 a1 = *(const f16x8*)(ax1 + k0);
    const f16x8 b0 = *(const f16x8*)(bx0 + k0);
    const f16x8 b1 = *(const f16x8*)(bx1 + k0);
    acc[0][0] = __builtin_amdgcn_mfma_f32_16x16x32_f16(a0, b0, acc[0][0], 0, 0, 0);
    acc[0][1] = __builtin_amdgcn_mfma_f32_16x16x32_f16(a0, b1, acc[0][1], 0, 0, 0);
    acc[1][0] = __builtin_amdgcn_mfma_f32_16x16x32_f16(a1, b0, acc[1][0], 0, 0, 0);
    acc[1][1] = __builtin_amdgcn_mfma_f32_16x16x32_f16(a1, b1, acc[1][1], 0, 0, 0);
  }
#pragma unroll
  for (int jn = 0; jn < 2; ++jn) {
    const int col = n0 + jn * 16 + fr;
    const float bb = b_ih[col] + b_hh[col];
#pragma unroll
    for (int i = 0; i < 2; ++i) {
#pragma unroll
      for (int rr = 0; rr < 4; ++rr) {
        const int row = m0 + i * 16 + kc * 4 + rr;   // D: col=lane&15, row=(lane>>4)*4+rr
        Gb[(size_t)row * RDIM + col] = f2h(acc[i][jn][rr] + bb);
      }
    }
  }
}

// ---------------- dependency precompute ----------------
__global__ __launch_bounds__(256) void prep_prev(
    const int* __restrict__ tok, int* __restrict__ prev)
{
  __shared__ int tl[T_TOTAL];
  for (int i = threadIdx.x; i < T_TOTAL; i += 256) tl[i] = tok[i];
  __syncthreads();
  const int t = blockIdx.x * 256 + threadIdx.x;
  const int my = tl[t];
  int p = -1;
  for (int u = t - 1; u >= 0; --u)
    if (tl[u] == my) { p = u; break; }
  prev[t] = p;
}

// ---------------- pipelined recurrence (f16 MFMA GEMV) ----------------
__global__ __launch_bounds__(512, 2) void lstm_pipe(
    const u16* __restrict__ Gb, const float* __restrict__ Whh,
    const int* __restrict__ prev,
    u64* __restrict__ mbox,    // [4096][256] stamped f32 c-slices (stamp==1)
    u32* __restrict__ hslot,   // [32][2][512] stamped f16 h, parity dbuf
    u32* __restrict__ xcdtab,  // [32][8] runtime XCD agreement (tag 0xC3)
    float* __restrict__ hs, float* __restrict__ last)
{
  const int bid = blockIdx.x;
  const int g  = bid & 31;       // sentence; bid%8 invariant -> same XCD (checked)
  const int wl = bid >> 5;       // local WG 0..7: owns hidden [wl*64, wl*64+64)
  const int tid = threadIdx.x;   // 0..511
  const int wv = tid >> 6;       // wave 0..7
  const int ln = tid & 63;
  const int fr = ln & 15;        // MFMA fragment row (M) / B col (N)
  const int kb = ln >> 4;        // k-subblock 0..3 (8 elems each)

  __shared__ u16 hh[HID];        // h as f16
  __shared__ float gsum[256];
  __shared__ u32 l2ok_sh;

  // runtime XCD check: publish own XCC_ID, then poll all 8 of this sentence
  const u32 myxcd = __builtin_amdgcn_s_getreg(20 | (31 << 11)) & 0xfu; // HW_REG_XCC_ID
  if (tid == 0) st32_dev(&xcdtab[(g << 3) + wl], 0xC3000000u | myxcd);

  // A-fragments (f16): wave wv owns row-blocks rb = 2wv, 2wv+1 (16 rows each).
  f16x8 areg[2][16];
#pragma unroll
  for (int b = 0; b < 2; ++b) {
    const int rb = wv * 2 + b;
    const int gg2 = rb >> 2, jb = rb & 3;
    const int grow = gg2 * HID + wl * 64 + jb * 16 + fr;
#pragma unroll
    for (int kc = 0; kc < 16; ++kc) {
      const float* src = &Whh[(size_t)grow * KDIM + kc * 32 + kb * 8];
      const float4 f0 = *(const float4*)src;
      const float4 f1 = *(const float4*)(src + 4);
      f16x8 a;
      a[0] = (f16)f0.x; a[1] = (f16)f0.y; a[2] = (f16)f0.z; a[3] = (f16)f0.w;
      a[4] = (f16)f1.x; a[5] = (f16)f1.y; a[6] = (f16)f1.z; a[7] = (f16)f1.w;
      areg[b][kc] = a;
    }
  }

  if (tid == 0) {
    u32 ok = 1;
    for (int k = 0; k < 8; ++k) {
      u32 v = ld32_dev(&xcdtab[(g << 3) + k]);
      while ((v >> 24) != 0xC3u) {
        __builtin_amdgcn_s_sleep(2);
        v = ld32_dev(&xcdtab[(g << 3) + k]);
      }
      if ((v & 0xfu) != myxcd) ok = 0;
    }
    l2ok_sh = ok;
  }
  __syncthreads();
  const bool l2x = (l2ok_sh != 0);

  u32* hsl = hslot + ((size_t)g << 10);   // this sentence's [2][512]
  const int j = wl * 64 + tid;            // hidden unit (valid tid<64)
  const int mcol = (wl - 4) * 64 + tid;   // memory col (valid wl>=4, tid<64)

  float c_reg = 0.f;

  for (int s = 0; s < Ssz; ++s) {
    const int t = g * Ssz + s;

    // ---- early issues: G row + memory-chain first probe ----
    u16 g0 = 0, g1 = 0, g2 = 0, g3 = 0;
    int pt = -1; u64 mv = 0;
    if (tid < 64) {
      const u16* gr = &Gb[(size_t)t * RDIM + wl * 64 + tid];
      g0 = gr[0]; g1 = gr[512]; g2 = gr[1024]; g3 = gr[1536];
      if (wl >= 4) {
        pt = prev[t];
        if (pt >= 0) mv = ld64_dev(&mbox[(size_t)pt * MSZ + mcol]);
      }
    }

    // ---- stage h_{s-1}: wave wv polls chunk wv (own chunk already in LDS) ----
    if (s == 0) {
      hh[wv * 64 + ln] = 0;
    } else if (wv != wl) {
      u32* sp = &hsl[((s & 1) << 9) + wv * 64 + ln];
      // fast path: L2-scope poll (publish is dev-scope, so L2 can't be
      // permanently stale); spin-count fallback to dev-scope = deadlock-proof
      u32 v = l2x ? ld32_l2(sp) : ld32_dev(sp);
      int spins = 0;
      while (!__all((v >> 16) == (u32)s)) {
        ++spins;
        if (l2x && spins < 4096) {
          v = ld32_l2(sp);
        } else {
          __builtin_amdgcn_s_sleep(1);
          v = ld32_dev(sp);
        }
      }
      hh[wv * 64 + ln] = (u16)v;
    }
    __syncthreads();

    // ---- GEMV via MFMA: 2 row-blocks x 16 kc, single f16 pass ----
    f32x4 acc0 = {}, acc1 = {};
    f16x8 bv = {};
#pragma unroll
    for (int kc = 0; kc < 16; ++kc) {
      if (fr == 0) bv = *(const f16x8*)&hh[kc * 32 + kb * 8];  // col-0 B lanes
      acc0 = __builtin_amdgcn_mfma_f32_16x16x32_f16(areg[0][kc], bv, acc0, 0, 0, 0);
      acc1 = __builtin_amdgcn_mfma_f32_16x16x32_f16(areg[1][kc], bv, acc1, 0, 0, 0);
    }
    if (fr == 0) {               // D col 0: lanes 0,16,32,48; rows kb*4+r
      *(f32x4*)&gsum[(wv * 2 + 0) * 16 + kb * 4] = acc0;
      *(f32x4*)&gsum[(wv * 2 + 1) * 16 + kb * 4] = acc1;
    }
    __syncthreads();

    // ---- LSTM cell: wave 0, one lane per hidden unit ----
    if (tid < 64) {
      const float zi = gsum[tid]       + h2f(g0);
      const float zf = gsum[64 + tid]  + h2f(g1);
      const float zg = gsum[128 + tid] + h2f(g2);
      const float zo = gsum[192 + tid] + h2f(g3);
      const float i_ = sigm_f(zi);
      const float f_ = sigm_f(zf);
      const float g_ = tanh_f(zg);
      const float o_ = sigm_f(zo);
      float cv;
      if (wl >= 4) {                       // spliced from cross-sentence chain
        if (pt >= 0) {
          while ((u32)(mv >> 32) != 1u) {
            __builtin_amdgcn_s_sleep(2);
            mv = ld64_dev(&mbox[(size_t)pt * MSZ + mcol]);
          }
          cv = __uint_as_float((u32)mv);
        } else {
          cv = 0.f;                        // initial memory = zeros
        }
      } else {                             // persistent cell, reset per sentence
        cv = (s == 0) ? 0.f : c_reg;
      }
      const float c2 = f_ * cv + i_ * g_;
      const float h2 = o_ * tanh_f(c2);
      c_reg = c2;

      // publish h (stamp s+1 in high16, f16 value low16): device scope always
      st32_dev(&hsl[(((s + 1) & 1) << 9) + j], ((u32)(s + 1) << 16) | (u32)f2h(h2));
      if (wl >= 4)                         // memory slice: device scope
        st64_dev(&mbox[(size_t)t * MSZ + mcol],
                 (1ull << 32) | (u64)__float_as_uint(c2));
      hh[j] = f2h(h2);                     // own chunk for next step
      hs[(size_t)t * HID + j] = h2;
      if (s == Ssz - 1) last[(size_t)g * HID + j] = h2;
    }
  }
}

extern "C" void kernel_launch(void* const* d_in, const int* in_sizes, int n_in,
                              void* d_out, int out_size, void* d_ws, size_t ws_size,
                              hipStream_t stream) {
  const float* x     = (const float*)d_in[0];  // [32,128,512]
  const int*   tok   = (const int*)d_in[1];    // [32,128]
  const float* W_ih  = (const float*)d_in[2];  // [2048,512]
  const float* W_hh  = (const float*)d_in[3];  // [2048,512]
  const float* b_ih  = (const float*)d_in[4];  // [2048]
  const float* b_hh  = (const float*)d_in[5];  // [2048]
  float*       out   = (float*)d_out;          // hs (4096*512) ++ last (32*512)

  char* ws = (char*)d_ws;
  u64* mbox   = (u64*)ws;                      // 8 MB      [0, 8388608)
  u32* hslot  = (u32*)(ws + 8388608);          // 128 KB
  int* prev   = (int*)(ws + 8519680);          // 16 KB
  u32* xcdtab = (u32*)(ws + 8536064);          // 1 KB
  u16* XW     = (u16*)(ws + 8540160);          // Xh 4 MB ++ Wh 2 MB
  u16* Xh     = XW;
  u16* Wh     = XW + NX;
  u16* Gb     = (u16*)(ws + 14831616);         // 16 MB   (total ~30.1 MB)

  // No memset: hslot stamps (==s in [1,128] high16), mbox (==1), xcdtab (0xC3)
  // are exact-checked; the 0xAA..A poison can never match any of them.

  cvt_f16<<<3072, 256, 0, stream>>>(x, W_ih, XW);
  prep_prev<<<T_TOTAL / 256, 256, 0, stream>>>(tok, prev);
  gemm_mfma<<<dim3(T_TOTAL / 64, RDIM / 64), 256, 0, stream>>>(Xh, Wh, b_ih, b_hh, Gb);
  lstm_pipe<<<256, 512, 0, stream>>>(Gb, W_hh, prev, mbox, hslot, xcdtab,
                                     out, out + (size_t)T_TOTAL * HID);
}

// Round 9
// 963.373 us; speedup vs baseline: 111.0238x; 111.0238x over previous
//
#include <hip/hip_runtime.h>
#include <hip/hip_bf16.h>

// MemoryLSTM: B=32, S=128, I=512, H=512, M=256, V=100000
// cvt_f16:   Xh,Wh = f16(X), f16(W_ih)
// gemm_mfma: Gb[4096][2048](f16) = Xh @ Wh^T + b_ih + b_hh   (MFMA 16x16x32 f16)
// prep_prev: prev[t] = latest t'<t with tok[t']==tok[t] (else -1)
// lstm_pipe: 32 sentences x 8 WGs x 512 thr, all concurrent.
//            GEMV via f16 MFMA single pass (R8-validated: absmax 3.9e-3).
//            ALL exchange device-scope sc0 sc1 (R8 lesson: sc0-only loads
//            CANNOT see another CU's sc0sc1 store -> L2 polling is broken).
//            Wave 0 (cell wave) never polls -> its store drain overlaps poll.

#define T_TOTAL 4096
#define Ssz 128
#define HID 512
#define RDIM 2048
#define KDIM 512
#define MSZ 256
#define NX (1 << 21)   // X elements (32*128*512)

typedef unsigned long long u64;
typedef unsigned int u32;
typedef unsigned short u16;
typedef _Float16 f16;
typedef __attribute__((ext_vector_type(8))) _Float16 f16x8;
typedef __attribute__((ext_vector_type(4))) float f32x4;

__device__ __forceinline__ u16 f2h(float x) {
  union { f16 h; u16 u; } c; c.h = (f16)x; return c.u;
}
__device__ __forceinline__ float h2f(u16 b) {
  union { f16 h; u16 u; } c; c.u = b; return (float)c.h;
}
__device__ __forceinline__ float sigm_f(float x) {
  return __builtin_amdgcn_rcpf(1.f + __expf(-x));
}
__device__ __forceinline__ float tanh_f(float x) {
  return 1.f - 2.f * __builtin_amdgcn_rcpf(1.f + __expf(2.f * x));
}

// Device-scope (die-level coherent) ops: sc0 sc1. Stamped words self-validate.
__device__ __forceinline__ u32 ld32_dev(const u32* p) {
  u32 v;
  asm volatile("global_load_dword %0, %1, off sc0 sc1\n\ts_waitcnt vmcnt(0)"
               : "=v"(v) : "v"(p) : "memory");
  return v;
}
__device__ __forceinline__ void st32_dev(u32* p, u32 v) {
  asm volatile("global_store_dword %0, %1, off sc0 sc1" :: "v"(p), "v"(v) : "memory");
}
__device__ __forceinline__ u64 ld64_dev(const u64* p) {
  u64 v;
  asm volatile("global_load_dwordx2 %0, %1, off sc0 sc1\n\ts_waitcnt vmcnt(0)"
               : "=v"(v) : "v"(p) : "memory");
  return v;
}
__device__ __forceinline__ void st64_dev(u64* p, u64 v) {
  asm volatile("global_store_dwordx2 %0, %1, off sc0 sc1" :: "v"(p), "v"(v) : "memory");
}

// ---------------- fp32 -> f16 convert (X ++ W_ih) ----------------
__global__ __launch_bounds__(256) void cvt_f16(
    const float* __restrict__ X, const float* __restrict__ W,
    u16* __restrict__ dst)
{
  const int i = (blockIdx.x * 256 + threadIdx.x) * 4;
  const float* s = (i < NX) ? &X[i] : &W[i - NX];
  const float4 v = *(const float4*)s;
  ushort4 o;
  o.x = f2h(v.x); o.y = f2h(v.y); o.z = f2h(v.z); o.w = f2h(v.w);
  *(ushort4*)&dst[i] = o;
}

// ---------------- Gb = f16(Xh @ Wh^T + b_ih + b_hh), MFMA ----------------
__global__ __launch_bounds__(256) void gemm_mfma(
    const u16* __restrict__ Xh, const u16* __restrict__ Wh,
    const float* __restrict__ b_ih, const float* __restrict__ b_hh,
    u16* __restrict__ Gb)
{
  const int tid = threadIdx.x;
  const int wave = tid >> 6;
  const int lane = tid & 63;
  const int wm = wave >> 1, wn = wave & 1;
  const int m0 = blockIdx.x * 64 + wm * 32;
  const int n0 = blockIdx.y * 64 + wn * 32;
  const int fr = lane & 15;
  const int kc = lane >> 4;

  f32x4 acc[2][2] = {};
  const u16* ax0 = &Xh[(size_t)(m0 + fr) * KDIM + kc * 8];
  const u16* ax1 = ax0 + 16 * KDIM;
  const u16* bx0 = &Wh[(size_t)(n0 + fr) * KDIM + kc * 8];
  const u16* bx1 = bx0 + 16 * KDIM;
#pragma unroll
  for (int k0 = 0; k0 < KDIM; k0 += 32) {
    const f16x8 a0 = *(const f16x8*)(ax0 + k0);
    const f16x8 a1 = *(const f16x8*)(ax1 + k0);
    const f16x8 b0 = *(const f16x8*)(bx0 + k0);
    const f16x8 b1 = *(const f16x8*)(bx1 + k0);
    acc[0][0] = __builtin_amdgcn_mfma_f32_16x16x32_f16(a0, b0, acc[0][0], 0, 0, 0);
    acc[0][1] = __builtin_amdgcn_mfma_f32_16x16x32_f16(a0, b1, acc[0][1], 0, 0, 0);
    acc[1][0] = __builtin_amdgcn_mfma_f32_16x16x32_f16(a1, b0, acc[1][0], 0, 0, 0);
    acc[1][1] = __builtin_amdgcn_mfma_f32_16x16x32_f16(a1, b1, acc[1][1], 0, 0, 0);
  }
#pragma unroll
  for (int jn = 0; jn < 2; ++jn) {
    const int col = n0 + jn * 16 + fr;
    const float bb = b_ih[col] + b_hh[col];
#pragma unroll
    for (int i = 0; i < 2; ++i) {
#pragma unroll
      for (int rr = 0; rr < 4; ++rr) {
        const int row = m0 + i * 16 + kc * 4 + rr;   // D: col=lane&15, row=(lane>>4)*4+rr
        Gb[(size_t)row * RDIM + col] = f2h(acc[i][jn][rr] + bb);
      }
    }
  }
}

// ---------------- dependency precompute ----------------
__global__ __launch_bounds__(256) void prep_prev(
    const int* __restrict__ tok, int* __restrict__ prev)
{
  __shared__ int tl[T_TOTAL];
  for (int i = threadIdx.x; i < T_TOTAL; i += 256) tl[i] = tok[i];
  __syncthreads();
  const int t = blockIdx.x * 256 + threadIdx.x;
  const int my = tl[t];
  int p = -1;
  for (int u = t - 1; u >= 0; --u)
    if (tl[u] == my) { p = u; break; }
  prev[t] = p;
}

// ---------------- pipelined recurrence (f16 MFMA GEMV) ----------------
__global__ __launch_bounds__(512, 2) void lstm_pipe(
    const u16* __restrict__ Gb, const float* __restrict__ Whh,
    const int* __restrict__ prev,
    u64* __restrict__ mbox,    // [4096][256] stamped f32 c-slices (stamp==1)
    u32* __restrict__ hslot,   // [32][2][512] stamped f16 h, parity dbuf
    float* __restrict__ hs, float* __restrict__ last)
{
  const int bid = blockIdx.x;
  const int g  = bid & 31;       // sentence; bid%8 invariant -> XCD locality
  const int wl = bid >> 5;       // local WG 0..7: owns hidden [wl*64, wl*64+64)
  const int tid = threadIdx.x;   // 0..511
  const int wv = tid >> 6;       // wave 0..7
  const int ln = tid & 63;
  const int fr = ln & 15;        // MFMA fragment row (M) / B col (N)
  const int kb = ln >> 4;        // k-subblock 0..3 (8 elems each)

  __shared__ u16 hh[HID];        // h as f16
  __shared__ float gsum[256];

  // A-fragments (f16): wave wv owns row-blocks rb = 2wv, 2wv+1 (16 rows each).
  f16x8 areg[2][16];
#pragma unroll
  for (int b = 0; b < 2; ++b) {
    const int rb = wv * 2 + b;
    const int gg2 = rb >> 2, jb = rb & 3;
    const int grow = gg2 * HID + wl * 64 + jb * 16 + fr;
#pragma unroll
    for (int kc = 0; kc < 16; ++kc) {
      const float* src = &Whh[(size_t)grow * KDIM + kc * 32 + kb * 8];
      const float4 f0 = *(const float4*)src;
      const float4 f1 = *(const float4*)(src + 4);
      f16x8 a;
      a[0] = (f16)f0.x; a[1] = (f16)f0.y; a[2] = (f16)f0.z; a[3] = (f16)f0.w;
      a[4] = (f16)f1.x; a[5] = (f16)f1.y; a[6] = (f16)f1.z; a[7] = (f16)f1.w;
      areg[b][kc] = a;
    }
  }

  // Poll assignment: waves 1..7 cover the 7 foreign chunks; wave 0 (the
  // cell/publisher wave) never polls, so its store drain overlaps the poll.
  const int pc = (wv <= wl) ? wv - 1 : wv;   // valid for wv>=1

  u32* hsl = hslot + ((size_t)g << 10);   // this sentence's [2][512]
  const int j = wl * 64 + tid;            // hidden unit (valid tid<64)
  const int mcol = (wl - 4) * 64 + tid;   // memory col (valid wl>=4, tid<64)

  float c_reg = 0.f;

  for (int s = 0; s < Ssz; ++s) {
    const int t = g * Ssz + s;

    // ---- early issues: G row + memory-chain first probe (wave 0) ----
    u16 g0 = 0, g1 = 0, g2 = 0, g3 = 0;
    int pt = -1; u64 mv = 0;
    if (tid < 64) {
      const u16* gr = &Gb[(size_t)t * RDIM + wl * 64 + tid];
      g0 = gr[0]; g1 = gr[512]; g2 = gr[1024]; g3 = gr[1536];
      if (wl >= 4) {
        pt = prev[t];
        if (pt >= 0) mv = ld64_dev(&mbox[(size_t)pt * MSZ + mcol]);
      }
    }

    // ---- stage h_{s-1}: waves 1..7 poll foreign chunks (dev scope) ----
    if (s == 0) {
      hh[tid] = 0;
    } else if (wv >= 1) {
      u32* sp = &hsl[((s & 1) << 9) + pc * 64 + ln];
      u32 v = ld32_dev(sp);
      while (!__all((v >> 16) == (u32)s)) {
        __builtin_amdgcn_s_sleep(1);
        v = ld32_dev(sp);
      }
      hh[pc * 64 + ln] = (u16)v;
    }
    __syncthreads();

    // ---- GEMV via MFMA: 2 row-blocks x 16 kc, 4 accumulators ----
    f32x4 acc0a = {}, acc0b = {}, acc1a = {}, acc1b = {};
    f16x8 bv = {};
#pragma unroll
    for (int kc = 0; kc < 8; ++kc) {
      if (fr == 0) bv = *(const f16x8*)&hh[kc * 32 + kb * 8];  // col-0 B lanes
      acc0a = __builtin_amdgcn_mfma_f32_16x16x32_f16(areg[0][kc], bv, acc0a, 0, 0, 0);
      acc1a = __builtin_amdgcn_mfma_f32_16x16x32_f16(areg[1][kc], bv, acc1a, 0, 0, 0);
    }
#pragma unroll
    for (int kc = 8; kc < 16; ++kc) {
      if (fr == 0) bv = *(const f16x8*)&hh[kc * 32 + kb * 8];
      acc0b = __builtin_amdgcn_mfma_f32_16x16x32_f16(areg[0][kc], bv, acc0b, 0, 0, 0);
      acc1b = __builtin_amdgcn_mfma_f32_16x16x32_f16(areg[1][kc], bv, acc1b, 0, 0, 0);
    }
    if (fr == 0) {               // D col 0: lanes 0,16,32,48; rows kb*4+r
      const f32x4 acc0 = acc0a + acc0b;
      const f32x4 acc1 = acc1a + acc1b;
      *(f32x4*)&gsum[(wv * 2 + 0) * 16 + kb * 4] = acc0;
      *(f32x4*)&gsum[(wv * 2 + 1) * 16 + kb * 4] = acc1;
    }
    __syncthreads();

    // ---- LSTM cell: wave 0, one lane per hidden unit ----
    if (tid < 64) {
      const float zi = gsum[tid]       + h2f(g0);
      const float zf = gsum[64 + tid]  + h2f(g1);
      const float zg = gsum[128 + tid] + h2f(g2);
      const float zo = gsum[192 + tid] + h2f(g3);
      const float i_ = sigm_f(zi);
      const float f_ = sigm_f(zf);
      const float g_ = tanh_f(zg);
      const float o_ = sigm_f(zo);
      float cv;
      if (wl >= 4) {                       // spliced from cross-sentence chain
        if (pt >= 0) {
          while ((u32)(mv >> 32) != 1u) {
            __builtin_amdgcn_s_sleep(2);
            mv = ld64_dev(&mbox[(size_t)pt * MSZ + mcol]);
          }
          cv = __uint_as_float((u32)mv);
        } else {
          cv = 0.f;                        // initial memory = zeros
        }
      } else {                             // persistent cell, reset per sentence
        cv = (s == 0) ? 0.f : c_reg;
      }
      const float c2 = f_ * cv + i_ * g_;
      const float h2 = o_ * tanh_f(c2);
      c_reg = c2;

      // publish h (stamp s+1 in high16, f16 value low16)
      st32_dev(&hsl[(((s + 1) & 1) << 9) + j], ((u32)(s + 1) << 16) | (u32)f2h(h2));
      if (wl >= 4)                         // memory slice (write-once)
        st64_dev(&mbox[(size_t)t * MSZ + mcol],
                 (1ull << 32) | (u64)__float_as_uint(c2));
      hh[j] = f2h(h2);                     // own chunk for next step
      hs[(size_t)t * HID + j] = h2;
      if (s == Ssz - 1) last[(size_t)g * HID + j] = h2;
    }
  }
}

extern "C" void kernel_launch(void* const* d_in, const int* in_sizes, int n_in,
                              void* d_out, int out_size, void* d_ws, size_t ws_size,
                              hipStream_t stream) {
  const float* x     = (const float*)d_in[0];  // [32,128,512]
  const int*   tok   = (const int*)d_in[1];    // [32,128]
  const float* W_ih  = (const float*)d_in[2];  // [2048,512]
  const float* W_hh  = (const float*)d_in[3];  // [2048,512]
  const float* b_ih  = (const float*)d_in[4];  // [2048]
  const float* b_hh  = (const float*)d_in[5];  // [2048]
  float*       out   = (float*)d_out;          // hs (4096*512) ++ last (32*512)

  char* ws = (char*)d_ws;
  u64* mbox   = (u64*)ws;                      // 8 MB      [0, 8388608)
  u32* hslot  = (u32*)(ws + 8388608);          // 128 KB
  int* prev   = (int*)(ws + 8519680);          // 16 KB
  u16* XW     = (u16*)(ws + 8536064);          // Xh 4 MB ++ Wh 2 MB
  u16* Xh     = XW;
  u16* Wh     = XW + NX;
  u16* Gb     = (u16*)(ws + 14827520);         // 16 MB   (total ~30.1 MB)

  // No memset: hslot stamps (==s in [1,128] high16) and mbox (==1) are
  // exact-checked; the 0xAA..A poison can never match either.

  cvt_f16<<<3072, 256, 0, stream>>>(x, W_ih, XW);
  prep_prev<<<T_TOTAL / 256, 256, 0, stream>>>(tok, prev);
  gemm_mfma<<<dim3(T_TOTAL / 64, RDIM / 64), 256, 0, stream>>>(Xh, Wh, b_ih, b_hh, Gb);
  lstm_pipe<<<256, 512, 0, stream>>>(Gb, W_hh, prev, mbox, hslot,
                                     out, out + (size_t)T_TOTAL * HID);
}

// Round 10
// 880.074 us; speedup vs baseline: 121.5323x; 1.0947x over previous
//
#include <hip/hip_runtime.h>
#include <hip/hip_bf16.h>

// MemoryLSTM: B=32, S=128, I=512, H=512, M=256, V=100000
// cvt_f16:   Xh,Wh = f16(X), f16(W_ih)
// gemm_mfma: Gb[4096][2048](f16) = Xh @ Wh^T + b_ih + b_hh   (MFMA 16x16x32 f16)
// prep_prev: prev[t] = latest t'<t with tok[t']==tok[t] (else -1) — branchless scan
// lstm_pipe: 32 sentences x 8 WGs x 512 thr, all concurrent.
//            PER-WAVE CELLS: wave wv owns hidden [wv*8,wv*8+8) x all 4 gates.
//            A-fragment rows remapped: block0={i,f}, block1={g,o}; D col0 puts
//            i,g on lanes 0,16 and f,o on lanes 32,48 -> one shfl_xor(32).
//            Each wave computes+publishes its own cells: no gsum, ONE barrier
//            per step, hh parity-double-buffered in LDS.
//            All exchange device-scope sc0 sc1 (R8 lesson: sc0-only loads
//            cannot observe another CU's sc0sc1 store).

#define T_TOTAL 4096
#define Ssz 128
#define HID 512
#define RDIM 2048
#define KDIM 512
#define MSZ 256
#define NX (1 << 21)   // X elements (32*128*512)

typedef unsigned long long u64;
typedef unsigned int u32;
typedef unsigned short u16;
typedef _Float16 f16;
typedef __attribute__((ext_vector_type(8))) _Float16 f16x8;
typedef __attribute__((ext_vector_type(4))) float f32x4;
typedef __attribute__((ext_vector_type(4))) u32 u32x4;

__device__ __forceinline__ u16 f2h(float x) {
  union { f16 h; u16 u; } c; c.h = (f16)x; return c.u;
}
__device__ __forceinline__ float h2f(u16 b) {
  union { f16 h; u16 u; } c; c.u = b; return (float)c.h;
}
__device__ __forceinline__ float sigm_f(float x) {
  return __builtin_amdgcn_rcpf(1.f + __expf(-x));
}
__device__ __forceinline__ float tanh_f(float x) {
  return 1.f - 2.f * __builtin_amdgcn_rcpf(1.f + __expf(2.f * x));
}

// Device-scope (die-level coherent) ops: sc0 sc1. Stamped words self-validate.
__device__ __forceinline__ u32 ld32_dev(const u32* p) {
  u32 v;
  asm volatile("global_load_dword %0, %1, off sc0 sc1\n\ts_waitcnt vmcnt(0)"
               : "=v"(v) : "v"(p) : "memory");
  return v;
}
// 32B stamped-c load: two dwordx4, one wait. Per-u64 stamps cover inter-store
// tearing; within one dwordx4 store no tearing (single 16B transaction).
__device__ __forceinline__ void ld_c4(const u64* p, u64 m[4]) {
  u32x4 a, b;
  asm volatile("global_load_dwordx4 %0, %2, off sc0 sc1\n\t"
               "global_load_dwordx4 %1, %2, off offset:16 sc0 sc1\n\t"
               "s_waitcnt vmcnt(0)"
               : "=&v"(a), "=&v"(b) : "v"(p) : "memory");
  m[0] = ((u64)a[1] << 32) | a[0];
  m[1] = ((u64)a[3] << 32) | a[2];
  m[2] = ((u64)b[1] << 32) | b[0];
  m[3] = ((u64)b[3] << 32) | b[2];
}
__device__ __forceinline__ void st_c4(u64* p, const u64 m[4]) {
  u32x4 a, b;
  a[0] = (u32)m[0]; a[1] = (u32)(m[0] >> 32);
  a[2] = (u32)m[1]; a[3] = (u32)(m[1] >> 32);
  b[0] = (u32)m[2]; b[1] = (u32)(m[2] >> 32);
  b[2] = (u32)m[3]; b[3] = (u32)(m[3] >> 32);
  asm volatile("global_store_dwordx4 %0, %1, off sc0 sc1\n\t"
               "global_store_dwordx4 %0, %2, off offset:16 sc0 sc1"
               :: "v"(p), "v"(a), "v"(b) : "memory");
}
__device__ __forceinline__ void st_h4(u32* p, u32x4 v) {
  asm volatile("global_store_dwordx4 %0, %1, off sc0 sc1" :: "v"(p), "v"(v) : "memory");
}

// ---------------- fp32 -> f16 convert (X ++ W_ih) ----------------
__global__ __launch_bounds__(256) void cvt_f16(
    const float* __restrict__ X, const float* __restrict__ W,
    u16* __restrict__ dst)
{
  const int i = (blockIdx.x * 256 + threadIdx.x) * 4;
  const float* s = (i < NX) ? &X[i] : &W[i - NX];
  const float4 v = *(const float4*)s;
  ushort4 o;
  o.x = f2h(v.x); o.y = f2h(v.y); o.z = f2h(v.z); o.w = f2h(v.w);
  *(ushort4*)&dst[i] = o;
}

// ---------------- Gb = f16(Xh @ Wh^T + b_ih + b_hh), MFMA ----------------
__global__ __launch_bounds__(256) void gemm_mfma(
    const u16* __restrict__ Xh, const u16* __restrict__ Wh,
    const float* __restrict__ b_ih, const float* __restrict__ b_hh,
    u16* __restrict__ Gb)
{
  const int tid = threadIdx.x;
  const int wave = tid >> 6;
  const int lane = tid & 63;
  const int wm = wave >> 1, wn = wave & 1;
  const int m0 = blockIdx.x * 64 + wm * 32;
  const int n0 = blockIdx.y * 64 + wn * 32;
  const int fr = lane & 15;
  const int kc = lane >> 4;

  f32x4 acc[2][2] = {};
  const u16* ax0 = &Xh[(size_t)(m0 + fr) * KDIM + kc * 8];
  const u16* ax1 = ax0 + 16 * KDIM;
  const u16* bx0 = &Wh[(size_t)(n0 + fr) * KDIM + kc * 8];
  const u16* bx1 = bx0 + 16 * KDIM;
#pragma unroll
  for (int k0 = 0; k0 < KDIM; k0 += 32) {
    const f16x8 a0 = *(const f16x8*)(ax0 + k0);
    const f16x8 a1 = *(const f16x8*)(ax1 + k0);
    const f16x8 b0 = *(const f16x8*)(bx0 + k0);
    const f16x8 b1 = *(const f16x8*)(bx1 + k0);
    acc[0][0] = __builtin_amdgcn_mfma_f32_16x16x32_f16(a0, b0, acc[0][0], 0, 0, 0);
    acc[0][1] = __builtin_amdgcn_mfma_f32_16x16x32_f16(a0, b1, acc[0][1], 0, 0, 0);
    acc[1][0] = __builtin_amdgcn_mfma_f32_16x16x32_f16(a1, b0, acc[1][0], 0, 0, 0);
    acc[1][1] = __builtin_amdgcn_mfma_f32_16x16x32_f16(a1, b1, acc[1][1], 0, 0, 0);
  }
#pragma unroll
  for (int jn = 0; jn < 2; ++jn) {
    const int col = n0 + jn * 16 + fr;
    const float bb = b_ih[col] + b_hh[col];
#pragma unroll
    for (int i = 0; i < 2; ++i) {
#pragma unroll
      for (int rr = 0; rr < 4; ++rr) {
        const int row = m0 + i * 16 + kc * 4 + rr;   // D: col=lane&15, row=(lane>>4)*4+rr
        Gb[(size_t)row * RDIM + col] = f2h(acc[i][jn][rr] + bb);
      }
    }
  }
}

// ---------------- dependency precompute (branchless, pipelined) ----------------
__global__ __launch_bounds__(256) void prep_prev(
    const int* __restrict__ tok, int* __restrict__ prev)
{
  __shared__ int tl[T_TOTAL];
  for (int i = threadIdx.x; i < T_TOTAL; i += 256) tl[i] = tok[i];
  __syncthreads();
  const int t = blockIdx.x * 256 + threadIdx.x;
  const int my = tl[t];
  int p = -1;
#pragma unroll 8
  for (int u = 0; u < t; ++u)
    p = (tl[u] == my) ? u : p;     // ascending scan, last match wins; no break
  prev[t] = p;
}

// ---------------- pipelined recurrence (per-wave cells) ----------------
__global__ __launch_bounds__(512, 2) void lstm_pipe(
    const u16* __restrict__ Gb, const float* __restrict__ Whh,
    const int* __restrict__ prev,
    u64* __restrict__ mbox,    // [4096][256] stamped f32 c-slices (stamp==1)
    u32* __restrict__ hslot,   // [32][2][512] stamped f16 h, parity dbuf
    float* __restrict__ hs, float* __restrict__ last)
{
  const int bid = blockIdx.x;
  const int g  = bid & 31;       // sentence; bid%8 invariant -> XCD locality
  const int wl = bid >> 5;       // local WG 0..7: owns hidden [wl*64, wl*64+64)
  const int tid = threadIdx.x;   // 0..511
  const int wv = tid >> 6;       // wave 0..7: owns hidden [wl*64+wv*8, +8), 4 gates
  const int ln = tid & 63;
  const int fr = ln & 15;        // A fragment row / B,D col
  const int kb = ln >> 4;        // k-subblock (inputs) / D row-block

  __shared__ u16 hh[2][HID];     // h_{s-1} as f16, parity double-buffered

  // A-fragments: block b covers gates {2b,2b+1} for hidden [wv*8,wv*8+8).
  // fragment row fr -> gate gg=2b+(fr>>3), hidden jj=fr&7.
  f16x8 areg[2][16];
#pragma unroll
  for (int b = 0; b < 2; ++b) {
    const int grow = (2 * b + (fr >> 3)) * HID + wl * 64 + wv * 8 + (fr & 7);
#pragma unroll
    for (int kc = 0; kc < 16; ++kc) {
      const float* src = &Whh[(size_t)grow * KDIM + kc * 32 + kb * 8];
      const float4 f0 = *(const float4*)src;
      const float4 f1 = *(const float4*)(src + 4);
      f16x8 a;
      a[0] = (f16)f0.x; a[1] = (f16)f0.y; a[2] = (f16)f0.z; a[3] = (f16)f0.w;
      a[4] = (f16)f1.x; a[5] = (f16)f1.y; a[6] = (f16)f1.z; a[7] = (f16)f1.w;
      areg[b][kc] = a;
    }
  }

  const int pc = (wv <= wl) ? wv - 1 : wv;       // foreign chunk (valid wv>=1)
  u32* hsl = hslot + ((size_t)g << 10);          // this sentence's [2][512]

  // cell lanes: ln 0 (jj 0-3) and ln 16 (jj 4-7); lanes 32,48 feed f,o via shfl
  const bool cellln = (fr == 0) && (kb < 2);
  const int jb = (ln & 16) ? 4 : 0;
  const int gsel = (ln >> 5) & 1;                // 0: i,g rows; 1: f,o rows
  const int jcol = wl * 64 + wv * 8 + jb;        // global hidden base (cell lanes)
  const int mc = (wl - 4) * 64 + wv * 8 + jb;    // mbox col base (wl>=4)

  f32x4 c_reg;
  c_reg[0] = 0.f; c_reg[1] = 0.f; c_reg[2] = 0.f; c_reg[3] = 0.f;

  for (int s = 0; s < Ssz; ++s) {
    const int t = g * Ssz + s;

    // ---- early issues: G rows (plain cached loads) + mbox first probe ----
    const ushort4 G0 = *(const ushort4*)&Gb[(size_t)t * RDIM + gsel * HID + jcol];
    const ushort4 G1 = *(const ushort4*)&Gb[(size_t)t * RDIM + (2 + gsel) * HID + jcol];
    int pt = -1; u64 m4[4] = {0, 0, 0, 0};
    if (wl >= 4 && cellln) {
      pt = prev[t];
      if (pt >= 0) ld_c4(&mbox[(size_t)pt * MSZ + mc], m4);
    }

    // ---- stage h_{s-1}: waves 1..7 poll foreign chunks (dev scope) ----
    if (s == 0) {
      hh[0][tid] = 0;
    } else if (wv >= 1) {
      u32* sp = &hsl[((s & 1) << 9) + pc * 64 + ln];
      u32 v = ld32_dev(sp);
      while (!__all((v >> 16) == (u32)s)) {
        __builtin_amdgcn_s_sleep(1);
        v = ld32_dev(sp);
      }
      hh[s & 1][pc * 64 + ln] = (u16)v;
    }
    __syncthreads();

    // ---- GEMV via MFMA: 2 gate-pair blocks x 16 kc, 4 accumulators ----
    f32x4 a0a = {}, a0b = {}, a1a = {}, a1b = {};
    f16x8 bv = {};
    const u16* hbuf = hh[s & 1];
#pragma unroll
    for (int kc = 0; kc < 8; ++kc) {
      if (fr == 0) bv = *(const f16x8*)&hbuf[kc * 32 + kb * 8];  // col-0 B lanes
      a0a = __builtin_amdgcn_mfma_f32_16x16x32_f16(areg[0][kc], bv, a0a, 0, 0, 0);
      a1a = __builtin_amdgcn_mfma_f32_16x16x32_f16(areg[1][kc], bv, a1a, 0, 0, 0);
    }
#pragma unroll
    for (int kc = 8; kc < 16; ++kc) {
      if (fr == 0) bv = *(const f16x8*)&hbuf[kc * 32 + kb * 8];
      a0b = __builtin_amdgcn_mfma_f32_16x16x32_f16(areg[0][kc], bv, a0b, 0, 0, 0);
      a1b = __builtin_amdgcn_mfma_f32_16x16x32_f16(areg[1][kc], bv, a1b, 0, 0, 0);
    }
    const f32x4 acc0 = a0a + a0b;   // D col0: lanes 0,16 = gate i; 32,48 = gate f
    const f32x4 acc1 = a1a + a1b;   // D col0: lanes 0,16 = gate g; 32,48 = gate o

    // pre-activations (+G) and cross-lane f,o delivery
    float z0[4], z1[4], zf[4], zo[4];
#pragma unroll
    for (int r = 0; r < 4; ++r) {
      z0[r] = acc0[r] + h2f((&G0.x)[r]);
      z1[r] = acc1[r] + h2f((&G1.x)[r]);
    }
#pragma unroll
    for (int r = 0; r < 4; ++r) {
      zf[r] = __shfl_xor(z0[r], 32, 64);   // lanes 0,16 receive f
      zo[r] = __shfl_xor(z1[r], 32, 64);   // lanes 0,16 receive o
    }

    // ---- cell: lanes 0,16 of EVERY wave (4 hidden units each) ----
    if (cellln) {
      f32x4 cv;
      if (wl >= 4) {                        // spliced from cross-sentence chain
        if (pt >= 0) {
          while (!((u32)(m4[0] >> 32) == 1u && (u32)(m4[1] >> 32) == 1u &&
                   (u32)(m4[2] >> 32) == 1u && (u32)(m4[3] >> 32) == 1u)) {
            __builtin_amdgcn_s_sleep(2);
            ld_c4(&mbox[(size_t)pt * MSZ + mc], m4);
          }
          cv[0] = __uint_as_float((u32)m4[0]); cv[1] = __uint_as_float((u32)m4[1]);
          cv[2] = __uint_as_float((u32)m4[2]); cv[3] = __uint_as_float((u32)m4[3]);
        } else {
          cv[0] = 0.f; cv[1] = 0.f; cv[2] = 0.f; cv[3] = 0.f;
        }
      } else {
        cv = c_reg;                         // zero-init covers s==0
      }
      u32x4 hp; u64 mo[4]; float4 hsv; ushort4 ho;
#pragma unroll
      for (int r = 0; r < 4; ++r) {
        const float i_ = sigm_f(z0[r]);
        const float f_ = sigm_f(zf[r]);
        const float g_ = tanh_f(z1[r]);
        const float o_ = sigm_f(zo[r]);
        const float c2 = f_ * cv[r] + i_ * g_;
        const float h2 = o_ * tanh_f(c2);
        c_reg[r] = c2;
        const u16 hb = f2h(h2);
        hp[r] = ((u32)(s + 1) << 16) | (u32)hb;
        mo[r] = (1ull << 32) | (u64)__float_as_uint(c2);
        (&hsv.x)[r] = h2;
        (&ho.x)[r] = hb;
      }
      // publish (stamp s+1): one 16B dev-scope store; mbox 32B; own chunk to LDS
      st_h4(&hsl[(((s + 1) & 1) << 9) + jcol], hp);
      if (wl >= 4) st_c4(&mbox[(size_t)t * MSZ + mc], mo);
      *(ushort4*)&hh[(s + 1) & 1][jcol] = ho;
      *(float4*)&hs[(size_t)t * HID + jcol] = hsv;
      if (s == Ssz - 1) *(float4*)&last[(size_t)g * HID + jcol] = hsv;
    }
  }
}

extern "C" void kernel_launch(void* const* d_in, const int* in_sizes, int n_in,
                              void* d_out, int out_size, void* d_ws, size_t ws_size,
                              hipStream_t stream) {
  const float* x     = (const float*)d_in[0];  // [32,128,512]
  const int*   tok   = (const int*)d_in[1];    // [32,128]
  const float* W_ih  = (const float*)d_in[2];  // [2048,512]
  const float* W_hh  = (const float*)d_in[3];  // [2048,512]
  const float* b_ih  = (const float*)d_in[4];  // [2048]
  const float* b_hh  = (const float*)d_in[5];  // [2048]
  float*       out   = (float*)d_out;          // hs (4096*512) ++ last (32*512)

  char* ws = (char*)d_ws;
  u64* mbox   = (u64*)ws;                      // 8 MB      [0, 8388608)
  u32* hslot  = (u32*)(ws + 8388608);          // 128 KB
  int* prev   = (int*)(ws + 8519680);          // 16 KB
  u16* XW     = (u16*)(ws + 8536064);          // Xh 4 MB ++ Wh 2 MB
  u16* Xh     = XW;
  u16* Wh     = XW + NX;
  u16* Gb     = (u16*)(ws + 14827520);         // 16 MB   (total ~30.1 MB)

  // No memset: hslot stamps (==s in [1,128] high16) and mbox (==1) are
  // exact-checked; the 0xAA..A poison can never match either.

  cvt_f16<<<3072, 256, 0, stream>>>(x, W_ih, XW);
  prep_prev<<<T_TOTAL / 256, 256, 0, stream>>>(tok, prev);
  gemm_mfma<<<dim3(T_TOTAL / 64, RDIM / 64), 256, 0, stream>>>(Xh, Wh, b_ih, b_hh, Gb);
  lstm_pipe<<<256, 512, 0, stream>>>(Gb, W_hh, prev, mbox, hslot,
                                     out, out + (size_t)T_TOTAL * HID);
}